// Round 1
// baseline (290.975 us; speedup 1.0000x reference)
//
#include <hip/hip_runtime.h>

// ---------------------------------------------------------------------------
// DeepseekV3 MoE: T=2048 tokens, H=1024, E=16 experts (top-4), I=512, SI=1024
// Sparse routed experts + shared expert, bf16 MFMA compute, fp32 routing.
// ---------------------------------------------------------------------------

#define T_TOK 2048
#define H_DIM 1024
#define E_NUM 16
#define I_DIM 512
#define SI_DIM 1024

typedef __bf16 bf16x8 __attribute__((ext_vector_type(8)));
typedef short short8 __attribute__((ext_vector_type(8)));
typedef float f32x4 __attribute__((ext_vector_type(4)));
typedef unsigned short u16;

struct alignas(8) U16x4 { u16 x, y, z, w; };
struct alignas(4) U16x2 { u16 x, y; };

__device__ __forceinline__ float bf2f(u16 u) {
    union { float f; unsigned int i; } v; v.i = ((unsigned int)u) << 16; return v.f;
}
__device__ __forceinline__ u16 f2bf(float f) {
    union { float f; unsigned int i; } v; v.f = f;
    unsigned int i = v.i;
    return (u16)((i + 0x7fffu + ((i >> 16) & 1u)) >> 16);   // RNE
}

// global -> LDS direct copy, 16B per lane. LDS dest must be wave-uniform base
// + lane*16 (it is: we pass base + tid*16 with tid linear in the wave).
#define GLOAD16(g, l)                                                          \
    __builtin_amdgcn_global_load_lds(                                          \
        (const __attribute__((address_space(1))) unsigned int*)(const void*)(g),\
        (__attribute__((address_space(3))) unsigned int*)(void*)(l), 16, 0, 0)

#define CNT(e) ((e) * 16)   // counts padded to one cacheline each

// ---------------------------------------------------------------------------
// K1: routing. One wave per token: fp32 scores = sigmoid(x . gw[e]), top-4
// (strict >, so ties pick lowest index like jax top_k), normalized weights.
// Builds per-expert compact token lists via atomics.
// ---------------------------------------------------------------------------
__global__ __launch_bounds__(256) void route_kernel(
    const float* __restrict__ x, const float* __restrict__ gw,
    int* __restrict__ cnt, int* __restrict__ tok,
    int* __restrict__ slot, float* __restrict__ wgt)
{
    const int wid  = threadIdx.x >> 6;
    const int lane = threadIdx.x & 63;
    const int t    = blockIdx.x * 4 + wid;

    const float* xp = x + (long)t * H_DIM;
    float xr[16];
#pragma unroll
    for (int j = 0; j < 16; ++j) xr[j] = xp[lane + 64 * j];

    float sc[E_NUM];
#pragma unroll
    for (int e = 0; e < E_NUM; ++e) {
        const float* gp = gw + e * H_DIM;
        float d = 0.f;
#pragma unroll
        for (int j = 0; j < 16; ++j) d += xr[j] * gp[lane + 64 * j];
#pragma unroll
        for (int off = 32; off; off >>= 1) d += __shfl_xor(d, off);
        sc[e] = 1.f / (1.f + expf(-d));      // sigmoid, all lanes hold it
    }

    // top-4 (all lanes redundantly; static indexing only — no scratch)
    float w[4]; int id[4];
    unsigned picked = 0;
    float sum = 0.f;
#pragma unroll
    for (int k = 0; k < 4; ++k) {
        float mv = -1.f; int mi = 0;
#pragma unroll
        for (int e = 0; e < E_NUM; ++e) {
            bool ok = !((picked >> e) & 1u) && (sc[e] > mv);
            mv = ok ? sc[e] : mv;
            mi = ok ? e : mi;
        }
        w[k] = mv; id[k] = mi; picked |= 1u << mi; sum += mv;
    }
    const float inv = 1.f / (sum + 1e-20f);

    if (lane == 0) {
#pragma unroll
        for (int k = 0; k < 4; ++k) {
            int pos = atomicAdd(&cnt[CNT(id[k])], 1);
            tok[id[k] * T_TOK + pos] = t;
            slot[t * 4 + k] = (id[k] << 16) | pos;
            wgt[t * 4 + k]  = w[k] * inv;
        }
    }
}

// K2: exclusive scan of counts -> compact row base per expert
__global__ void scan_kernel(const int* __restrict__ cnt, int* __restrict__ ebase)
{
    if (threadIdx.x == 0) {
        int s = 0;
        for (int e = 0; e < E_NUM; ++e) { ebase[e] = s; s += cnt[CNT(e)]; }
    }
}

// K3: x (fp32) -> bf16, vectorized
__global__ __launch_bounds__(256) void convert_kernel(
    const float* __restrict__ in, u16* __restrict__ out)
{
    const int i = (blockIdx.x * 256 + threadIdx.x) * 4;
    float4 v = *(const float4*)&in[i];
    U16x4 o = { f2bf(v.x), f2bf(v.y), f2bf(v.z), f2bf(v.w) };
    *(U16x4*)&out[i] = o;
}

// K4: transpose-convert [batch][R][C] fp32 -> [batch][C][R] bf16.
// Grid: (C/64, R/64, batch). 64x64 fp32 tile in LDS, padded stride 65.
__global__ __launch_bounds__(256) void transpose_cv(
    const float* __restrict__ in, u16* __restrict__ out, int R, int C)
{
    __shared__ float tl[64][65];
    const long boff = (long)blockIdx.z * R * C;
    const int r0 = blockIdx.y * 64, c0 = blockIdx.x * 64;
    const int tid = threadIdx.x;

#pragma unroll
    for (int p = 0; p < 16; ++p) {
        int row = p * 4 + (tid >> 6), col = tid & 63;
        tl[row][col] = in[boff + (long)(r0 + row) * C + (c0 + col)];
    }
    __syncthreads();
#pragma unroll
    for (int p = 0; p < 8; ++p) {
        int cc = p * 8 + (tid >> 5), rp = (tid & 31) * 2;
        U16x2 o = { f2bf(tl[rp][cc]), f2bf(tl[rp + 1][cc]) };
        *(U16x2*)&out[boff + (long)(c0 + cc) * R + (r0 + rp)] = o;
    }
}

// ---------------------------------------------------------------------------
// K5: bf16 GEMM, tile 128(M) x 64(N), BK=64, 256 threads = 4 waves (2x2),
// wave tile 64x32, mfma_f32_16x16x32_bf16. A:[rows][K] bf16 (optionally
// gathered through a token list), B:[N][K] bf16 (pre-transposed weights).
// LDS chunk-XOR swizzle (phys_chunk = chunk ^ (row&7)) applied on BOTH the
// pre-swizzled global source and the ds_read address (involution).
// DUAL: two B matrices, epilogue silu(g)*u. OUTF32: fp32 plain store.
// ---------------------------------------------------------------------------
template<bool DUAL, bool GATHER, bool OUTF32>
__global__ __launch_bounds__(256) void gemm_bf16(
    const u16* __restrict__ A, const u16* __restrict__ B1,
    const u16* __restrict__ B2, void* __restrict__ Out,
    const int* __restrict__ cnt, const int* __restrict__ ebase,
    const int* __restrict__ tok, int Mfixed, int K, int Ntot, long sB)
{
    const int e  = blockIdx.z;
    const int M  = cnt ? cnt[CNT(e)] : Mfixed;
    const int m0 = blockIdx.y * 128;
    if (m0 >= M) return;
    const int n0 = blockIdx.x * 64;
    const int rbase = ebase ? ebase[e] : 0;
    const u16* b1p = B1 + (long)e * sB;
    const u16* b2p = DUAL ? (B2 + (long)e * sB) : B1;

    __shared__ __attribute__((aligned(16))) u16 sA[128 * 64];
    __shared__ __attribute__((aligned(16))) u16 sB1t[64 * 64];
    __shared__ __attribute__((aligned(16))) u16 sB2t[DUAL ? 64 * 64 : 8];

    const int tid  = threadIdx.x;
    const int lane = tid & 63;
    const int wid  = tid >> 6;
    const int wr   = wid >> 1;   // wave row in 2x2
    const int wc   = wid & 1;    // wave col

    // A staging source pointers (per-thread; kt added in the loop).
    // slot q -> (row=q>>3, phys chunk s=q&7); load global chunk s^(row&7).
    const u16* aptr[4];
#pragma unroll
    for (int i = 0; i < 4; ++i) {
        int q = i * 256 + tid;
        int row = q >> 3, s = q & 7;
        int r = m0 + row; if (r >= M) r = M - 1;           // clamp, masked at C
        long grow = GATHER ? (long)tok[e * T_TOK + r] : (long)(rbase + r);
        aptr[i] = A + grow * K + ((s ^ (row & 7)) << 3);
    }
    const u16* bptr1[2]; const u16* bptr2[2];
#pragma unroll
    for (int i = 0; i < 2; ++i) {
        int q = i * 256 + tid;
        int row = q >> 3, s = q & 7;
        long go = (long)(n0 + row) * K + ((s ^ (row & 7)) << 3);
        bptr1[i] = b1p + go;
        bptr2[i] = b2p + go;
    }

    f32x4 accG[4][2], accU[4][2];
#pragma unroll
    for (int i = 0; i < 4; ++i)
#pragma unroll
        for (int j = 0; j < 2; ++j) {
            accG[i][j] = (f32x4){0.f, 0.f, 0.f, 0.f};
            if (DUAL) accU[i][j] = (f32x4){0.f, 0.f, 0.f, 0.f};
        }

    for (int kt = 0; kt < K; kt += 64) {
        __syncthreads();                     // previous tile fully consumed
#pragma unroll
        for (int i = 0; i < 4; ++i) GLOAD16(aptr[i] + kt, &sA[(i * 256 + tid) * 8]);
#pragma unroll
        for (int i = 0; i < 2; ++i) {
            GLOAD16(bptr1[i] + kt, &sB1t[(i * 256 + tid) * 8]);
            if (DUAL) GLOAD16(bptr2[i] + kt, &sB2t[(i * 256 + tid) * 8]);
        }
        asm volatile("s_waitcnt vmcnt(0)" ::: "memory");
        __syncthreads();

#pragma unroll
        for (int ks = 0; ks < 2; ++ks) {
            bf16x8 a[4], bg[2], bu[2];
#pragma unroll
            for (int mf = 0; mf < 4; ++mf) {
                int row = wr * 64 + mf * 16 + (lane & 15);
                int c   = ks * 4 + (lane >> 4);
                a[mf] = __builtin_bit_cast(bf16x8,
                    *(const short8*)&sA[row * 64 + ((c ^ (row & 7)) << 3)]);
            }
#pragma unroll
            for (int nf = 0; nf < 2; ++nf) {
                int row = wc * 32 + nf * 16 + (lane & 15);
                int c   = ks * 4 + (lane >> 4);
                int o   = row * 64 + ((c ^ (row & 7)) << 3);
                bg[nf] = __builtin_bit_cast(bf16x8, *(const short8*)&sB1t[o]);
                if (DUAL) bu[nf] = __builtin_bit_cast(bf16x8, *(const short8*)&sB2t[o]);
            }
#pragma unroll
            for (int mf = 0; mf < 4; ++mf)
#pragma unroll
                for (int nf = 0; nf < 2; ++nf) {
                    accG[mf][nf] = __builtin_amdgcn_mfma_f32_16x16x32_bf16(
                        a[mf], bg[nf], accG[mf][nf], 0, 0, 0);
                    if (DUAL)
                        accU[mf][nf] = __builtin_amdgcn_mfma_f32_16x16x32_bf16(
                            a[mf], bu[nf], accU[mf][nf], 0, 0, 0);
                }
        }
    }

    // epilogue: C/D layout col = lane&15, row = (lane>>4)*4 + reg  [m89]
#pragma unroll
    for (int mf = 0; mf < 4; ++mf)
#pragma unroll
        for (int nf = 0; nf < 2; ++nf)
#pragma unroll
            for (int r = 0; r < 4; ++r) {
                int row = m0 + wr * 64 + mf * 16 + (lane >> 4) * 4 + r;
                if (row >= M) continue;
                int col = n0 + wc * 32 + nf * 16 + (lane & 15);
                float v = accG[mf][nf][r];
                if constexpr (DUAL) {
                    float uu = accU[mf][nf][r];
                    v = v / (1.f + expf(-v)) * uu;       // silu(g)*u
                }
                long oidx = (long)(rbase + row) * Ntot + col;
                if constexpr (OUTF32) ((float*)Out)[oidx] = v;
                else                  ((u16*)Out)[oidx]   = f2bf(v);
            }
}

// ---------------------------------------------------------------------------
// K6: combine. out[t] (already = shared_out) += sum_k w_k * pair[base+pos].
// Deterministic: fixed k-order per token, no atomics.
// ---------------------------------------------------------------------------
__global__ __launch_bounds__(256) void combine_kernel(
    float* __restrict__ out, const u16* __restrict__ pair,
    const int* __restrict__ slot, const float* __restrict__ wgt,
    const int* __restrict__ ebase)
{
    const int t = blockIdx.x;
    const int c = threadIdx.x * 4;
    float4 o = *(float4*)&out[(long)t * H_DIM + c];
#pragma unroll
    for (int k = 0; k < 4; ++k) {
        int s = slot[t * 4 + k];
        int e = s >> 16, pos = s & 0xffff;
        float w = wgt[t * 4 + k];
        const u16* pr = pair + (long)(ebase[e] + pos) * H_DIM + c;
        U16x4 pv = *(const U16x4*)pr;
        o.x += w * bf2f(pv.x);
        o.y += w * bf2f(pv.y);
        o.z += w * bf2f(pv.z);
        o.w += w * bf2f(pv.w);
    }
    *(float4*)&out[(long)t * H_DIM + c] = o;
}

// ---------------------------------------------------------------------------
extern "C" void kernel_launch(void* const* d_in, const int* in_sizes, int n_in,
                              void* d_out, int out_size, void* d_ws, size_t ws_size,
                              hipStream_t stream)
{
    const float* x  = (const float*)d_in[0];  // [1,2048,1024]
    const float* gw = (const float*)d_in[1];  // [16,1024]
    const float* eg = (const float*)d_in[2];  // [16,1024,512]
    const float* eu = (const float*)d_in[3];  // [16,1024,512]
    const float* ed = (const float*)d_in[4];  // [16,512,1024]
    const float* sg = (const float*)d_in[5];  // [1024,1024]
    const float* su = (const float*)d_in[6];  // [1024,1024]
    const float* sd = (const float*)d_in[7];  // [1024,1024]
    float* out = (float*)d_out;

    unsigned char* w = (unsigned char*)d_ws;
    size_t off = 0;
    auto alloc = [&](size_t b) -> void* {
        off = (off + 255) & ~(size_t)255;
        void* p = w + off; off += b; return p;
    };
    int*   cnt   = (int*)  alloc(256 * 4);                       // padded counts
    int*   ebase = (int*)  alloc(16 * 4);
    int*   tok   = (int*)  alloc((size_t)E_NUM * T_TOK * 4);
    int*   slot  = (int*)  alloc((size_t)T_TOK * 4 * 4);
    float* wgt   = (float*)alloc((size_t)T_TOK * 4 * 4);
    u16*   xb    = (u16*)  alloc((size_t)T_TOK * H_DIM * 2);
    u16*   egT   = (u16*)  alloc((size_t)E_NUM * I_DIM * H_DIM * 2);
    u16*   euT   = (u16*)  alloc((size_t)E_NUM * I_DIM * H_DIM * 2);
    u16*   edT   = (u16*)  alloc((size_t)E_NUM * H_DIM * I_DIM * 2);
    u16*   sgT   = (u16*)  alloc((size_t)SI_DIM * H_DIM * 2);
    u16*   suT   = (u16*)  alloc((size_t)SI_DIM * H_DIM * 2);
    u16*   sdT   = (u16*)  alloc((size_t)H_DIM * SI_DIM * 2);
    u16*   actR  = (u16*)  alloc((size_t)T_TOK * 4 * I_DIM * 2); // 8192 x 512
    u16*   actS  = (u16*)  alloc((size_t)T_TOK * SI_DIM * 2);    // 2048 x 1024
    u16*   pair  = (u16*)  alloc((size_t)T_TOK * 4 * H_DIM * 2); // 8192 x 1024

    hipMemsetAsync(cnt, 0, 256 * 4, stream);

    route_kernel<<<T_TOK / 4, 256, 0, stream>>>(x, gw, cnt, tok, slot, wgt);
    scan_kernel<<<1, 64, 0, stream>>>(cnt, ebase);

    convert_kernel<<<T_TOK * H_DIM / 1024, 256, 0, stream>>>(x, xb);
    transpose_cv<<<dim3(I_DIM / 64, H_DIM / 64, E_NUM), 256, 0, stream>>>(eg, egT, H_DIM, I_DIM);
    transpose_cv<<<dim3(I_DIM / 64, H_DIM / 64, E_NUM), 256, 0, stream>>>(eu, euT, H_DIM, I_DIM);
    transpose_cv<<<dim3(H_DIM / 64, I_DIM / 64, E_NUM), 256, 0, stream>>>(ed, edT, I_DIM, H_DIM);
    transpose_cv<<<dim3(16, 16, 1), 256, 0, stream>>>(sg, sgT, H_DIM, SI_DIM);
    transpose_cv<<<dim3(16, 16, 1), 256, 0, stream>>>(su, suT, H_DIM, SI_DIM);
    transpose_cv<<<dim3(16, 16, 1), 256, 0, stream>>>(sd, sdT, SI_DIM, H_DIM);

    // routed gate+up (gather tokens, silu(g)*u -> actR bf16 [8192][512])
    gemm_bf16<true, true, false><<<dim3(I_DIM / 64, 16, E_NUM), 256, 0, stream>>>(
        xb, egT, euT, actR, cnt, ebase, tok, 0, H_DIM, I_DIM, (long)I_DIM * H_DIM);
    // shared gate+up -> actS bf16 [2048][1024]
    gemm_bf16<true, false, false><<<dim3(SI_DIM / 64, T_TOK / 128, 1), 256, 0, stream>>>(
        xb, sgT, suT, actS, nullptr, nullptr, nullptr, T_TOK, H_DIM, SI_DIM, 0);
    // routed down: actR @ edT -> pair bf16 [8192][1024]
    gemm_bf16<false, false, false><<<dim3(H_DIM / 64, 16, E_NUM), 256, 0, stream>>>(
        actR, edT, nullptr, pair, cnt, ebase, nullptr, 0, I_DIM, H_DIM, (long)H_DIM * I_DIM);
    // shared down: actS @ sdT -> d_out fp32 (plain store, becomes the base)
    gemm_bf16<false, false, true><<<dim3(H_DIM / 64, T_TOK / 128, 1), 256, 0, stream>>>(
        actS, sdT, nullptr, out, nullptr, nullptr, nullptr, T_TOK, SI_DIM, H_DIM, 0);

    combine_kernel<<<T_TOK, 256, 0, stream>>>(out, pair, slot, wgt, ebase);
}